// Round 2
// baseline (9386.584 us; speedup 1.0000x reference)
//
#include <hip/hip_runtime.h>

// ---------------------------------------------------------------------------
// 2-layer tanh RNN, B=64, T=512, I=256, H=512.  Round 2: persistent pipelined
// scan kernel.
//   - batches split into 4 groups of 16 (independent); cols split 8 blocks of
//     64; per layer: 32 blocks. 64 blocks total, all co-resident.
//   - weight B-fragments (fp16) live in VGPRs for the whole T loop (layer0:
//     24 frags, layer1: 32 frags). No LDS, no per-step weight traffic.
//   - cross-block h exchange via out0 slabs / h1 ping-pong in ws + per-(g,t)
//     arrival counters (agent-scope release atomics, acquire fence on wait).
//   - layer1@t starts as soon as layer0@t published -> layers overlap.
// ---------------------------------------------------------------------------

#define kB 64
#define kT 512
#define kI 256
#define kH 512
#define kBH (kB * kH)   // 32768

typedef _Float16 half8 __attribute__((ext_vector_type(8)));
typedef _Float16 half4v __attribute__((ext_vector_type(4)));
typedef float floatx4 __attribute__((ext_vector_type(4)));

// ws layout (bytes)
constexpr size_t X16_B   = 0;                              // [B][T][I] fp16
constexpr size_t OUT0M_B = 16777216;                       // [T+1][B][H] fp16 (slab s = h output of step s-1; slab 0 = h init)
constexpr size_t H1BUF_B = OUT0M_B + (size_t)(kT + 1) * kBH * 2;  // [2][B][H] fp16
constexpr size_t CNT_B   = H1BUF_B + (size_t)2 * kBH * 2;  // cnt0[4][512], cnt1[4][512] int

__device__ inline half8 cvt8(const float* p) {
    const float4* p4 = (const float4*)p;
    float4 a = p4[0], b = p4[1];
    half8 h;
    h[0] = (_Float16)a.x; h[1] = (_Float16)a.y; h[2] = (_Float16)a.z; h[3] = (_Float16)a.w;
    h[4] = (_Float16)b.x; h[5] = (_Float16)b.y; h[6] = (_Float16)b.z; h[7] = (_Float16)b.w;
    return h;
}

__device__ inline void wait_flag(const int* p, int target) {
    int guard = 0;
    while (__hip_atomic_load(p, __ATOMIC_RELAXED, __HIP_MEMORY_SCOPE_AGENT) < target) {
        if (++guard > 100000000) break;  // fail-wrong, not hang
    }
    __threadfence();  // acquire: invalidate so slab loads see producer data
}

__global__ void cvt_x_kernel(const float* __restrict__ x, _Float16* __restrict__ x16) {
    size_t i = ((size_t)blockIdx.x * blockDim.x + threadIdx.x) * 4;
    size_t stride = (size_t)gridDim.x * blockDim.x * 4;
    const size_t n = (size_t)kB * kT * kI;
    for (; i < n; i += stride) {
        float4 v = *(const float4*)(x + i);
        half4v h;
        h[0] = (_Float16)v.x; h[1] = (_Float16)v.y; h[2] = (_Float16)v.z; h[3] = (_Float16)v.w;
        *(half4v*)(x16 + i) = h;
    }
}

// h_0 -> out0m slab 0 (layer0 init) and h1buf[1] (layer1 init, read at t=0); zero counters
__global__ void setup_kernel(const float* __restrict__ h0, _Float16* __restrict__ out0m,
                             _Float16* __restrict__ h1buf, int* __restrict__ cnt) {
    int idx = blockIdx.x * blockDim.x + threadIdx.x;  // 0 .. 65535
    if (idx < kBH) out0m[idx] = (_Float16)h0[idx];
    else h1buf[idx] = (_Float16)h0[idx];  // idx-kBH into buf[1] == h1buf[idx]
    if (idx < 4096) cnt[idx] = 0;
}

__global__ __launch_bounds__(256) void scan_kernel(
    const _Float16* __restrict__ x16, _Float16* __restrict__ out0m,
    _Float16* __restrict__ h1buf, int* __restrict__ cnt0, int* __restrict__ cnt1,
    float* __restrict__ out1,
    const float* __restrict__ wih0, const float* __restrict__ whh0,
    const float* __restrict__ bih0, const float* __restrict__ bhh0,
    const float* __restrict__ wih1, const float* __restrict__ whh1,
    const float* __restrict__ bih1, const float* __restrict__ bhh1) {
    const int blk = blockIdx.x;
    const int tid = threadIdx.x;
    const int wave = tid >> 6;
    const int lane = tid & 63;
    const int r = lane & 15;   // row selector (A: batch, B: col)
    const int q = lane >> 4;   // k-chunk selector
    const int layer = blk >> 5;
    const int lb = blk & 31;
    const int g = lb >> 3;     // batch group 0..3
    const int j = lb & 7;      // col block 0..7
    const int c = j * 64 + wave * 16 + r;  // output column 0..511
    const int b0 = g * 16;     // batch base

    if (layer == 0) {
        // ---------------- layer 0 ----------------
        half8 wf[8], hf[16];
#pragma unroll
        for (int m = 0; m < 8; ++m) wf[m] = cvt8(wih0 + (size_t)c * kI + m * 32 + q * 8);
#pragma unroll
        for (int m = 0; m < 16; ++m) hf[m] = cvt8(whh0 + (size_t)c * kH + m * 32 + q * 8);
        const float bias = bih0[c] + bhh0[c];
        int* flags = cnt0 + g * kT;

        for (int t = 0; t < kT; ++t) {
            floatx4 ax = {0.f, 0.f, 0.f, 0.f};
            floatx4 ah = {0.f, 0.f, 0.f, 0.f};
            // x projection: x16[b0+r][t][k], K=256
            const _Float16* xrow = x16 + (((size_t)(b0 + r) * kT + t) * kI) + q * 8;
#pragma unroll
            for (int m = 0; m < 8; ++m) {
                half8 a = *(const half8*)(xrow + m * 32);
                ax = __builtin_amdgcn_mfma_f32_16x16x32_f16(a, wf[m], ax, 0, 0, 0);
            }
            // gate: h slab t (written by step t-1) must be published
            if (t > 0) wait_flag(&flags[t - 1], 32);
            const _Float16* hrow = out0m + (size_t)t * kBH + (size_t)(b0 + r) * kH + q * 8;
#pragma unroll
            for (int m = 0; m < 16; ++m) {
                half8 a = *(const half8*)(hrow + m * 32);
                ah = __builtin_amdgcn_mfma_f32_16x16x32_f16(a, hf[m], ah, 0, 0, 0);
            }
            _Float16* osl = out0m + (size_t)(t + 1) * kBH;
#pragma unroll
            for (int i = 0; i < 4; ++i) {
                float v = tanhf(ax[i] + ah[i] + bias);
                osl[(size_t)(b0 + q * 4 + i) * kH + c] = (_Float16)v;
            }
            if (lane == 0)
                __hip_atomic_fetch_add(&flags[t], 1, __ATOMIC_RELEASE, __HIP_MEMORY_SCOPE_AGENT);
        }
    } else {
        // ---------------- layer 1 ----------------
        half8 wf[16], hf[16];
#pragma unroll
        for (int m = 0; m < 16; ++m) wf[m] = cvt8(wih1 + (size_t)c * kH + m * 32 + q * 8);
#pragma unroll
        for (int m = 0; m < 16; ++m) hf[m] = cvt8(whh1 + (size_t)c * kH + m * 32 + q * 8);
        const float bias = bih1[c] + bhh1[c];
        int* flags0 = cnt0 + g * kT;
        int* flags1 = cnt1 + g * kT;

        for (int t = 0; t < kT; ++t) {
            floatx4 ax = {0.f, 0.f, 0.f, 0.f};
            floatx4 ah = {0.f, 0.f, 0.f, 0.f};
            // gate 1: out0[t] (= slab t+1) published by layer0
            wait_flag(&flags0[t], 32);
            const _Float16* irow = out0m + (size_t)(t + 1) * kBH + (size_t)(b0 + r) * kH + q * 8;
#pragma unroll
            for (int m = 0; m < 16; ++m) {
                half8 a = *(const half8*)(irow + m * 32);
                ax = __builtin_amdgcn_mfma_f32_16x16x32_f16(a, wf[m], ax, 0, 0, 0);
            }
            // gate 2: own h state from t-1
            if (t > 0) wait_flag(&flags1[t - 1], 32);
            const _Float16* hrow = h1buf + (size_t)((t & 1) ^ 1) * kBH + (size_t)(b0 + r) * kH + q * 8;
#pragma unroll
            for (int m = 0; m < 16; ++m) {
                half8 a = *(const half8*)(hrow + m * 32);
                ah = __builtin_amdgcn_mfma_f32_16x16x32_f16(a, hf[m], ah, 0, 0, 0);
            }
            _Float16* h1w = h1buf + (size_t)(t & 1) * kBH;
#pragma unroll
            for (int i = 0; i < 4; ++i) {
                const int b_ = b0 + q * 4 + i;
                float v = tanhf(ax[i] + ah[i] + bias);
                out1[((size_t)b_ * kT + t) * kH + c] = v;
                h1w[(size_t)b_ * kH + c] = (_Float16)v;
            }
            if (lane == 0)
                __hip_atomic_fetch_add(&flags1[t], 1, __ATOMIC_RELEASE, __HIP_MEMORY_SCOPE_AGENT);
        }
    }
}

__global__ void finalize_kernel(const _Float16* __restrict__ out0m,
                                const _Float16* __restrict__ h1buf,
                                float* __restrict__ out) {
    int idx = blockIdx.x * blockDim.x + threadIdx.x;  // 0 .. 65535
    float* hn = out + (size_t)kB * kT * kH;
    if (idx < kBH) hn[idx] = (float)out0m[(size_t)kT * kBH + idx];  // slab T = h0 final
    else hn[idx] = (float)h1buf[idx];  // buf[1] = h1 final (t=511 odd)
}

extern "C" void kernel_launch(void* const* d_in, const int* in_sizes, int n_in,
                              void* d_out, int out_size, void* d_ws, size_t ws_size,
                              hipStream_t stream) {
    const float* x    = (const float*)d_in[0];
    const float* h0in = (const float*)d_in[1];
    const float* wih0 = (const float*)d_in[2];
    const float* whh0 = (const float*)d_in[3];
    const float* bih0 = (const float*)d_in[4];
    const float* bhh0 = (const float*)d_in[5];
    const float* wih1 = (const float*)d_in[6];
    const float* whh1 = (const float*)d_in[7];
    const float* bih1 = (const float*)d_in[8];
    const float* bhh1 = (const float*)d_in[9];
    float* out = (float*)d_out;
    char* ws = (char*)d_ws;

    _Float16* x16   = (_Float16*)(ws + X16_B);
    _Float16* out0m = (_Float16*)(ws + OUT0M_B);
    _Float16* h1buf = (_Float16*)(ws + H1BUF_B);
    int* cnt        = (int*)(ws + CNT_B);
    int* cnt0 = cnt;
    int* cnt1 = cnt + 4 * kT;

    cvt_x_kernel<<<1024, 256, 0, stream>>>(x, x16);
    setup_kernel<<<(2 * kBH) / 256, 256, 0, stream>>>(h0in, out0m, h1buf, cnt);
    scan_kernel<<<64, 256, 0, stream>>>(x16, out0m, h1buf, cnt0, cnt1, out,
                                        wih0, whh0, bih0, bhh0, wih1, whh1, bih1, bhh1);
    finalize_kernel<<<(2 * kBH) / 256, 256, 0, stream>>>(out0m, h1buf, out);
}

// Round 3
// 3817.860 us; speedup vs baseline: 2.4586x; 2.4586x over previous
//
#include <hip/hip_runtime.h>

// ---------------------------------------------------------------------------
// 2-layer tanh RNN, B=64, T=512, I=256, H=512.  Round 3: persistent pipelined
// scan, fence-free cross-block sync.
//   - 64 blocks x 256 thr: 4 batch-groups x 8 col-blocks x 2 layers.
//   - weights in VGPRs for entire scan (__launch_bounds__(256,1) -> 512 VGPR
//     budget; R2's 100-VGPR alloc rematerialized weight loads every step).
//   - h exchange: relaxed agent atomic stores (write-through to LLC, no
//     cache-wide flush) + s_waitcnt vmcnt(0) + relaxed atomic flag. Consumers
//     poll flag (LLC) then read slabs with NORMAL loads -- safe because both
//     out0m and h1m are (T+1)-slab rotating buffers: every slab address is
//     first-touch, so no stale L1/L2 line can exist. No buffer_inv/wbl2.
// ---------------------------------------------------------------------------

#define kB 64
#define kT 512
#define kI 256
#define kH 512
#define kBH (kB * kH)   // 32768

typedef _Float16 half8 __attribute__((ext_vector_type(8)));
typedef _Float16 half4v __attribute__((ext_vector_type(4)));
typedef float floatx4 __attribute__((ext_vector_type(4)));

// ws layout (bytes)
constexpr size_t X16_B   = 0;                                    // [B][T][I] fp16
constexpr size_t OUT0M_B = 16u * 1024 * 1024;                    // [T+1][B][H] fp16
constexpr size_t H1M_B   = OUT0M_B + (size_t)(kT + 1) * kBH * 2; // [T+1][B][H] fp16
constexpr size_t CNT_B   = H1M_B + (size_t)(kT + 1) * kBH * 2;   // cnt0[4][512], cnt1[4][512]

__device__ inline half8 cvt8(const float* p) {
    const float4* p4 = (const float4*)p;
    float4 a = p4[0], b = p4[1];
    half8 h;
    h[0] = (_Float16)a.x; h[1] = (_Float16)a.y; h[2] = (_Float16)a.z; h[3] = (_Float16)a.w;
    h[4] = (_Float16)b.x; h[5] = (_Float16)b.y; h[6] = (_Float16)b.z; h[7] = (_Float16)b.w;
    return h;
}

__device__ inline void sc_store_half(_Float16* p, _Float16 v) {
    unsigned short u = __builtin_bit_cast(unsigned short, v);
    __hip_atomic_store((unsigned short*)p, u, __ATOMIC_RELAXED, __HIP_MEMORY_SCOPE_AGENT);
}

__device__ inline void wait_flag(const int* p, int target) {
    int guard = 0;
    while (__hip_atomic_load(p, __ATOMIC_RELAXED, __HIP_MEMORY_SCOPE_AGENT) < target) {
        if (++guard > 200000000) break;  // fail-wrong, not hang
    }
    asm volatile("" ::: "memory");  // no hoisting of slab loads above the gate
}

// per-wave publish: drain this wave's sc1 stores to LLC, then bump flag.
__device__ inline void publish(int* p, int lane) {
    asm volatile("" ::: "memory");
    __builtin_amdgcn_s_waitcnt(0x0F70);  // vmcnt(0), lgkm/exp don't-care
    asm volatile("" ::: "memory");
    if (lane == 0)
        __hip_atomic_fetch_add(p, 1, __ATOMIC_RELAXED, __HIP_MEMORY_SCOPE_AGENT);
}

__global__ void cvt_x_kernel(const float* __restrict__ x, _Float16* __restrict__ x16) {
    size_t i = ((size_t)blockIdx.x * blockDim.x + threadIdx.x) * 4;
    size_t stride = (size_t)gridDim.x * blockDim.x * 4;
    const size_t n = (size_t)kB * kT * kI;
    for (; i < n; i += stride) {
        float4 v = *(const float4*)(x + i);
        half4v h;
        h[0] = (_Float16)v.x; h[1] = (_Float16)v.y; h[2] = (_Float16)v.z; h[3] = (_Float16)v.w;
        *(half4v*)(x16 + i) = h;
    }
}

// h_0 -> out0m slab 0 and h1m slab 0; zero counters
__global__ void setup_kernel(const float* __restrict__ h0, _Float16* __restrict__ out0m,
                             _Float16* __restrict__ h1m, int* __restrict__ cnt) {
    int idx = blockIdx.x * blockDim.x + threadIdx.x;  // 0 .. 65535
    if (idx < kBH) out0m[idx] = (_Float16)h0[idx];
    else h1m[idx - kBH] = (_Float16)h0[idx];
    if (idx < 4096) cnt[idx] = 0;
}

__global__ __launch_bounds__(256, 1) void scan_kernel(
    const _Float16* __restrict__ x16, _Float16* __restrict__ out0m,
    _Float16* __restrict__ h1m, int* __restrict__ cnt0, int* __restrict__ cnt1,
    float* __restrict__ out1,
    const float* __restrict__ wih0, const float* __restrict__ whh0,
    const float* __restrict__ bih0, const float* __restrict__ bhh0,
    const float* __restrict__ wih1, const float* __restrict__ whh1,
    const float* __restrict__ bih1, const float* __restrict__ bhh1) {
    const int blk = blockIdx.x;
    const int tid = threadIdx.x;
    const int wave = tid >> 6;
    const int lane = tid & 63;
    const int r = lane & 15;   // row selector (A: batch, B: col)
    const int q = lane >> 4;   // k-chunk selector
    const int layer = blk >> 5;
    const int lb = blk & 31;
    const int g = lb >> 3;     // batch group 0..3
    const int j = lb & 7;      // col block 0..7
    const int c = j * 64 + wave * 16 + r;  // output column 0..511
    const int b0 = g * 16;     // batch base

    if (layer == 0) {
        // ---------------- layer 0 ----------------
        half8 wf[8], hfw[16];
#pragma unroll
        for (int m = 0; m < 8; ++m) wf[m] = cvt8(wih0 + (size_t)c * kI + m * 32 + q * 8);
#pragma unroll
        for (int m = 0; m < 16; ++m) hfw[m] = cvt8(whh0 + (size_t)c * kH + m * 32 + q * 8);
        const float bias = bih0[c] + bhh0[c];
        int* flags = cnt0 + g * kT;

        for (int t = 0; t < kT; ++t) {
            floatx4 ax = {0.f, 0.f, 0.f, 0.f};
            floatx4 a0 = {0.f, 0.f, 0.f, 0.f};
            floatx4 a1 = {0.f, 0.f, 0.f, 0.f};
            // x projection (off critical path, before the gate)
            const _Float16* xrow = x16 + ((size_t)(b0 + r) * kT + t) * kI + q * 8;
#pragma unroll
            for (int m = 0; m < 8; ++m) {
                half8 a = *(const half8*)(xrow + m * 32);
                ax = __builtin_amdgcn_mfma_f32_16x16x32_f16(a, wf[m], ax, 0, 0, 0);
            }
            if (t > 0) wait_flag(&flags[t - 1], 32);
            const _Float16* hrow = out0m + (size_t)t * kBH + (size_t)(b0 + r) * kH + q * 8;
#pragma unroll
            for (int m = 0; m < 16; m += 2) {
                half8 a = *(const half8*)(hrow + m * 32);
                half8 b = *(const half8*)(hrow + (m + 1) * 32);
                a0 = __builtin_amdgcn_mfma_f32_16x16x32_f16(a, hfw[m], a0, 0, 0, 0);
                a1 = __builtin_amdgcn_mfma_f32_16x16x32_f16(b, hfw[m + 1], a1, 0, 0, 0);
            }
            _Float16* osl = out0m + (size_t)(t + 1) * kBH;
#pragma unroll
            for (int i = 0; i < 4; ++i) {
                float v = tanhf(ax[i] + a0[i] + a1[i] + bias);
                sc_store_half(osl + (size_t)(b0 + q * 4 + i) * kH + c, (_Float16)v);
            }
            publish(&flags[t], lane);
        }
    } else {
        // ---------------- layer 1 ----------------
        half8 wf[16], hfw[16];
#pragma unroll
        for (int m = 0; m < 16; ++m) wf[m] = cvt8(wih1 + (size_t)c * kH + m * 32 + q * 8);
#pragma unroll
        for (int m = 0; m < 16; ++m) hfw[m] = cvt8(whh1 + (size_t)c * kH + m * 32 + q * 8);
        const float bias = bih1[c] + bhh1[c];
        int* flags0 = cnt0 + g * kT;
        int* flags1 = cnt1 + g * kT;

        for (int t = 0; t < kT; ++t) {
            floatx4 x0 = {0.f, 0.f, 0.f, 0.f};
            floatx4 x1 = {0.f, 0.f, 0.f, 0.f};
            floatx4 a0 = {0.f, 0.f, 0.f, 0.f};
            floatx4 a1 = {0.f, 0.f, 0.f, 0.f};
            // gate 1: layer0 output for t (slab t+1)
            wait_flag(&flags0[t], 32);
            const _Float16* irow = out0m + (size_t)(t + 1) * kBH + (size_t)(b0 + r) * kH + q * 8;
#pragma unroll
            for (int m = 0; m < 16; m += 2) {
                half8 a = *(const half8*)(irow + m * 32);
                half8 b = *(const half8*)(irow + (m + 1) * 32);
                x0 = __builtin_amdgcn_mfma_f32_16x16x32_f16(a, wf[m], x0, 0, 0, 0);
                x1 = __builtin_amdgcn_mfma_f32_16x16x32_f16(b, wf[m + 1], x1, 0, 0, 0);
            }
            // gate 2: own h from t-1 (slab t)
            if (t > 0) wait_flag(&flags1[t - 1], 32);
            const _Float16* hrow = h1m + (size_t)t * kBH + (size_t)(b0 + r) * kH + q * 8;
#pragma unroll
            for (int m = 0; m < 16; m += 2) {
                half8 a = *(const half8*)(hrow + m * 32);
                half8 b = *(const half8*)(hrow + (m + 1) * 32);
                a0 = __builtin_amdgcn_mfma_f32_16x16x32_f16(a, hfw[m], a0, 0, 0, 0);
                a1 = __builtin_amdgcn_mfma_f32_16x16x32_f16(b, hfw[m + 1], a1, 0, 0, 0);
            }
            _Float16* h1w = h1m + (size_t)(t + 1) * kBH;
#pragma unroll
            for (int i = 0; i < 4; ++i) {
                const int b_ = b0 + q * 4 + i;
                float v = tanhf(x0[i] + x1[i] + a0[i] + a1[i] + bias);
                out1[((size_t)b_ * kT + t) * kH + c] = v;        // fp32, normal store
                sc_store_half(h1w + (size_t)b_ * kH + c, (_Float16)v);
            }
            publish(&flags1[t], lane);
        }
    }
}

__global__ void finalize_kernel(const _Float16* __restrict__ out0m,
                                const _Float16* __restrict__ h1m,
                                float* __restrict__ out) {
    int idx = blockIdx.x * blockDim.x + threadIdx.x;  // 0 .. 65535
    float* hn = out + (size_t)kB * kT * kH;
    if (idx < kBH) hn[idx] = (float)out0m[(size_t)kT * kBH + idx];
    else hn[idx] = (float)h1m[(size_t)kT * kBH + (idx - kBH)];
}

extern "C" void kernel_launch(void* const* d_in, const int* in_sizes, int n_in,
                              void* d_out, int out_size, void* d_ws, size_t ws_size,
                              hipStream_t stream) {
    const float* x    = (const float*)d_in[0];
    const float* h0in = (const float*)d_in[1];
    const float* wih0 = (const float*)d_in[2];
    const float* whh0 = (const float*)d_in[3];
    const float* bih0 = (const float*)d_in[4];
    const float* bhh0 = (const float*)d_in[5];
    const float* wih1 = (const float*)d_in[6];
    const float* whh1 = (const float*)d_in[7];
    const float* bih1 = (const float*)d_in[8];
    const float* bhh1 = (const float*)d_in[9];
    float* out = (float*)d_out;
    char* ws = (char*)d_ws;

    _Float16* x16   = (_Float16*)(ws + X16_B);
    _Float16* out0m = (_Float16*)(ws + OUT0M_B);
    _Float16* h1m   = (_Float16*)(ws + H1M_B);
    int* cnt        = (int*)(ws + CNT_B);
    int* cnt0 = cnt;
    int* cnt1 = cnt + 4 * kT;

    cvt_x_kernel<<<1024, 256, 0, stream>>>(x, x16);
    setup_kernel<<<(2 * kBH) / 256, 256, 0, stream>>>(h0in, out0m, h1m, cnt);
    scan_kernel<<<64, 256, 0, stream>>>(x16, out0m, h1m, cnt0, cnt1, out,
                                        wih0, whh0, bih0, bhh0, wih1, whh1, bih1, bhh1);
    finalize_kernel<<<(2 * kBH) / 256, 256, 0, stream>>>(out0m, h1m, out);
}

// Round 4
// 2181.982 us; speedup vs baseline: 4.3019x; 1.7497x over previous
//
#include <hip/hip_runtime.h>

// ---------------------------------------------------------------------------
// 2-layer tanh RNN, B=64, T=512, I=256, H=512.  Round 4: K-split waves so
// weight fragments actually fit in registers.
//   - 256 blocks x 256 thr = 2 layers x 4 batch-groups x 32 col-tiles(16).
//     1 block/CU, all co-resident.
//   - each block owns one 16x16 output tile; its 4 waves split K (128 each).
//     Weight frags/wave: layer1 32 VGPRs, layer0 24 -> no remat (R2/R3 failed
//     because ~128+ weight VGPRs made the compiler reload weights every step;
//     FETCH_SIZE 445 MB and VGPR_Count=104 proved it).
//   - cross-wave combine: 8 KB double-buffered LDS + one barrier; tanh and
//     store distributed (1 elem/lane).
//   - cross-block h exchange: rotating (T+1)-slab buffers, relaxed agent
//     atomic stores (to LLC) + vmcnt drain + relaxed flag add; consumers poll
//     flag then read slabs with normal loads (first-touch addresses -> no
//     stale lines). No cache-wide fences anywhere.
// ---------------------------------------------------------------------------

#define kB 64
#define kT 512
#define kI 256
#define kH 512
#define kBH (kB * kH)   // 32768

typedef _Float16 half8 __attribute__((ext_vector_type(8)));
typedef _Float16 half4v __attribute__((ext_vector_type(4)));
typedef float floatx4 __attribute__((ext_vector_type(4)));

// ws layout (bytes)
constexpr size_t X16_B   = 0;                                    // [B][T][I] fp16
constexpr size_t OUT0M_B = 16u * 1024 * 1024;                    // [T+1][B][H] fp16
constexpr size_t H1M_B   = OUT0M_B + (size_t)(kT + 1) * kBH * 2; // [T+1][B][H] fp16
constexpr size_t CNT_B   = H1M_B + (size_t)(kT + 1) * kBH * 2;   // cnt0[4][512], cnt1[4][512]

__device__ inline half8 cvt8(const float* p) {
    const float4* p4 = (const float4*)p;
    float4 a = p4[0], b = p4[1];
    half8 h;
    h[0] = (_Float16)a.x; h[1] = (_Float16)a.y; h[2] = (_Float16)a.z; h[3] = (_Float16)a.w;
    h[4] = (_Float16)b.x; h[5] = (_Float16)b.y; h[6] = (_Float16)b.z; h[7] = (_Float16)b.w;
    return h;
}

__device__ inline void sc_store_half(_Float16* p, _Float16 v) {
    unsigned short u = __builtin_bit_cast(unsigned short, v);
    __hip_atomic_store((unsigned short*)p, u, __ATOMIC_RELAXED, __HIP_MEMORY_SCOPE_AGENT);
}

__device__ inline void wait_flag(const int* p, int target) {
    int guard = 0;
    while (__hip_atomic_load(p, __ATOMIC_RELAXED, __HIP_MEMORY_SCOPE_AGENT) < target) {
        if (++guard > 20000000) break;  // fail-wrong, not hang
    }
    asm volatile("" ::: "memory");  // keep slab loads below the gate
}

// per-wave publish: drain this wave's stores to LLC, then bump flag.
__device__ inline void publish(int* p, int lane) {
    asm volatile("" ::: "memory");
    __builtin_amdgcn_s_waitcnt(0x0F70);  // vmcnt(0)
    asm volatile("" ::: "memory");
    if (lane == 0)
        __hip_atomic_fetch_add(p, 1, __ATOMIC_RELAXED, __HIP_MEMORY_SCOPE_AGENT);
}

__global__ void cvt_x_kernel(const float* __restrict__ x, _Float16* __restrict__ x16) {
    size_t i = ((size_t)blockIdx.x * blockDim.x + threadIdx.x) * 4;
    size_t stride = (size_t)gridDim.x * blockDim.x * 4;
    const size_t n = (size_t)kB * kT * kI;
    for (; i < n; i += stride) {
        float4 v = *(const float4*)(x + i);
        half4v h;
        h[0] = (_Float16)v.x; h[1] = (_Float16)v.y; h[2] = (_Float16)v.z; h[3] = (_Float16)v.w;
        *(half4v*)(x16 + i) = h;
    }
}

__global__ void setup_kernel(const float* __restrict__ h0, _Float16* __restrict__ out0m,
                             _Float16* __restrict__ h1m, int* __restrict__ cnt) {
    int idx = blockIdx.x * blockDim.x + threadIdx.x;  // 0 .. 65535
    if (idx < kBH) out0m[idx] = (_Float16)h0[idx];
    else h1m[idx - kBH] = (_Float16)h0[idx];
    if (idx < 4096) cnt[idx] = 0;
}

__global__ __launch_bounds__(256, 1) void scan_kernel(
    const _Float16* __restrict__ x16, _Float16* __restrict__ out0m,
    _Float16* __restrict__ h1m, int* __restrict__ cnt0, int* __restrict__ cnt1,
    float* __restrict__ out1,
    const float* __restrict__ wih0, const float* __restrict__ whh0,
    const float* __restrict__ bih0, const float* __restrict__ bhh0,
    const float* __restrict__ wih1, const float* __restrict__ whh1,
    const float* __restrict__ bih1, const float* __restrict__ bhh1) {
    __shared__ float lds[2][4][256];   // [parity][wave][tile elems], 8 KB

    const int blk = blockIdx.x;
    const int tid = threadIdx.x;
    const int wave = tid >> 6;
    const int lane = tid & 63;
    const int r = lane & 15;   // MFMA row selector (A: batch, B: col)
    const int q = lane >> 4;   // MFMA k-subchunk
    const int layer = blk >> 7;
    const int lb = blk & 127;
    const int g = lb >> 5;             // batch group 0..3
    const int ct = lb & 31;            // col tile 0..31
    const int c0 = ct * 16;
    const int b0 = g * 16;

    // reduction-role mapping: this thread finalizes elem (row, col) of the tile
    const int col = lane & 15;
    const int row = wave * 4 + (lane >> 4);
    const int cc = c0 + col;           // output column
    const int bb = b0 + row;           // output batch
    const int roff = (wave * 16 + col) * 4 + (lane >> 4);  // LDS read offset within a partial

    if (layer == 0) {
        // ---------------- layer 0 ----------------
        half8 wfi[2], wfh[4];
#pragma unroll
        for (int m = 0; m < 2; ++m)
            wfi[m] = cvt8(wih0 + (size_t)(c0 + r) * kI + wave * 64 + m * 32 + q * 8);
#pragma unroll
        for (int m = 0; m < 4; ++m)
            wfh[m] = cvt8(whh0 + (size_t)(c0 + r) * kH + wave * 128 + m * 32 + q * 8);
        const float bias = bih0[cc] + bhh0[cc];
        int* flags = cnt0 + g * kT;

        for (int t = 0; t < kT; ++t) {
            // x projection for this wave's K-slice (pre-gate, latency-hidden)
            const _Float16* xrow = x16 + ((size_t)(b0 + r) * kT + t) * kI + wave * 64 + q * 8;
            half8 xa0 = *(const half8*)(xrow);
            half8 xa1 = *(const half8*)(xrow + 32);
            floatx4 a0 = {0.f, 0.f, 0.f, 0.f};
            floatx4 a1 = {0.f, 0.f, 0.f, 0.f};
            a0 = __builtin_amdgcn_mfma_f32_16x16x32_f16(xa0, wfi[0], a0, 0, 0, 0);
            a1 = __builtin_amdgcn_mfma_f32_16x16x32_f16(xa1, wfi[1], a1, 0, 0, 0);

            if (t > 0) wait_flag(&flags[t - 1], 128);
            const _Float16* hrow = out0m + (size_t)t * kBH + (size_t)(b0 + r) * kH
                                   + wave * 128 + q * 8;
            half8 h0v = *(const half8*)(hrow);
            half8 h1v = *(const half8*)(hrow + 32);
            half8 h2v = *(const half8*)(hrow + 64);
            half8 h3v = *(const half8*)(hrow + 96);
            a0 = __builtin_amdgcn_mfma_f32_16x16x32_f16(h0v, wfh[0], a0, 0, 0, 0);
            a1 = __builtin_amdgcn_mfma_f32_16x16x32_f16(h1v, wfh[1], a1, 0, 0, 0);
            a0 = __builtin_amdgcn_mfma_f32_16x16x32_f16(h2v, wfh[2], a0, 0, 0, 0);
            a1 = __builtin_amdgcn_mfma_f32_16x16x32_f16(h3v, wfh[3], a1, 0, 0, 0);

            *(floatx4*)(&lds[t & 1][wave][lane * 4]) = a0 + a1;
            __syncthreads();
            const float* lp = &lds[t & 1][0][0];
            float s = lp[roff] + lp[256 + roff] + lp[512 + roff] + lp[768 + roff];
            float v = tanhf(s + bias);
            sc_store_half(out0m + (size_t)(t + 1) * kBH + (size_t)bb * kH + cc, (_Float16)v);
            publish(&flags[t], lane);
        }
    } else {
        // ---------------- layer 1 ----------------
        half8 wfi[4], wfh[4];
#pragma unroll
        for (int m = 0; m < 4; ++m)
            wfi[m] = cvt8(wih1 + (size_t)(c0 + r) * kH + wave * 128 + m * 32 + q * 8);
#pragma unroll
        for (int m = 0; m < 4; ++m)
            wfh[m] = cvt8(whh1 + (size_t)(c0 + r) * kH + wave * 128 + m * 32 + q * 8);
        const float bias = bih1[cc] + bhh1[cc];
        int* flags0 = cnt0 + g * kT;
        int* flags1 = cnt1 + g * kT;

        for (int t = 0; t < kT; ++t) {
            floatx4 a0 = {0.f, 0.f, 0.f, 0.f};
            floatx4 a1 = {0.f, 0.f, 0.f, 0.f};
            // gate 1: layer0 output for t (slab t+1)
            wait_flag(&flags0[t], 128);
            const _Float16* irow = out0m + (size_t)(t + 1) * kBH + (size_t)(b0 + r) * kH
                                   + wave * 128 + q * 8;
            half8 i0 = *(const half8*)(irow);
            half8 i1 = *(const half8*)(irow + 32);
            half8 i2 = *(const half8*)(irow + 64);
            half8 i3 = *(const half8*)(irow + 96);
            a0 = __builtin_amdgcn_mfma_f32_16x16x32_f16(i0, wfi[0], a0, 0, 0, 0);
            a1 = __builtin_amdgcn_mfma_f32_16x16x32_f16(i1, wfi[1], a1, 0, 0, 0);
            a0 = __builtin_amdgcn_mfma_f32_16x16x32_f16(i2, wfi[2], a0, 0, 0, 0);
            a1 = __builtin_amdgcn_mfma_f32_16x16x32_f16(i3, wfi[3], a1, 0, 0, 0);
            // gate 2: own h from t-1 (slab t)
            if (t > 0) wait_flag(&flags1[t - 1], 128);
            const _Float16* hrow = h1m + (size_t)t * kBH + (size_t)(b0 + r) * kH
                                   + wave * 128 + q * 8;
            half8 h0v = *(const half8*)(hrow);
            half8 h1v = *(const half8*)(hrow + 32);
            half8 h2v = *(const half8*)(hrow + 64);
            half8 h3v = *(const half8*)(hrow + 96);
            a0 = __builtin_amdgcn_mfma_f32_16x16x32_f16(h0v, wfh[0], a0, 0, 0, 0);
            a1 = __builtin_amdgcn_mfma_f32_16x16x32_f16(h1v, wfh[1], a1, 0, 0, 0);
            a0 = __builtin_amdgcn_mfma_f32_16x16x32_f16(h2v, wfh[2], a0, 0, 0, 0);
            a1 = __builtin_amdgcn_mfma_f32_16x16x32_f16(h3v, wfh[3], a1, 0, 0, 0);

            *(floatx4*)(&lds[t & 1][wave][lane * 4]) = a0 + a1;
            __syncthreads();
            const float* lp = &lds[t & 1][0][0];
            float s = lp[roff] + lp[256 + roff] + lp[512 + roff] + lp[768 + roff];
            float v = tanhf(s + bias);
            out1[((size_t)bb * kT + t) * kH + cc] = v;   // fp32 output, normal store
            sc_store_half(h1m + (size_t)(t + 1) * kBH + (size_t)bb * kH + cc, (_Float16)v);
            publish(&flags1[t], lane);
        }
    }
}

__global__ void finalize_kernel(const _Float16* __restrict__ out0m,
                                const _Float16* __restrict__ h1m,
                                float* __restrict__ out) {
    int idx = blockIdx.x * blockDim.x + threadIdx.x;  // 0 .. 65535
    float* hn = out + (size_t)kB * kT * kH;
    if (idx < kBH) hn[idx] = (float)out0m[(size_t)kT * kBH + idx];
    else hn[idx] = (float)h1m[(size_t)kT * kBH + (idx - kBH)];
}

extern "C" void kernel_launch(void* const* d_in, const int* in_sizes, int n_in,
                              void* d_out, int out_size, void* d_ws, size_t ws_size,
                              hipStream_t stream) {
    const float* x    = (const float*)d_in[0];
    const float* h0in = (const float*)d_in[1];
    const float* wih0 = (const float*)d_in[2];
    const float* whh0 = (const float*)d_in[3];
    const float* bih0 = (const float*)d_in[4];
    const float* bhh0 = (const float*)d_in[5];
    const float* wih1 = (const float*)d_in[6];
    const float* whh1 = (const float*)d_in[7];
    const float* bih1 = (const float*)d_in[8];
    const float* bhh1 = (const float*)d_in[9];
    float* out = (float*)d_out;
    char* ws = (char*)d_ws;

    _Float16* x16   = (_Float16*)(ws + X16_B);
    _Float16* out0m = (_Float16*)(ws + OUT0M_B);
    _Float16* h1m   = (_Float16*)(ws + H1M_B);
    int* cnt        = (int*)(ws + CNT_B);
    int* cnt0 = cnt;
    int* cnt1 = cnt + 4 * kT;

    cvt_x_kernel<<<1024, 256, 0, stream>>>(x, x16);
    setup_kernel<<<(2 * kBH) / 256, 256, 0, stream>>>(h0in, out0m, h1m, cnt);
    scan_kernel<<<256, 256, 0, stream>>>(x16, out0m, h1m, cnt0, cnt1, out,
                                         wih0, whh0, bih0, bhh0, wih1, whh1, bih1, bhh1);
    finalize_kernel<<<(2 * kBH) / 256, 256, 0, stream>>>(out0m, h1m, out);
}

// Round 5
// 2096.684 us; speedup vs baseline: 4.4769x; 1.0407x over previous
//
#include <hip/hip_runtime.h>

// ---------------------------------------------------------------------------
// 2-layer tanh RNN, B=64, T=512, I=256, H=512.  Round 5: contention-free
// publish/poll (R4 serialized 128 atomic RMWs on one flag dword per step).
//   - 256 blocks x 256 thr = 2 layers x 4 batch-groups x 32 col-tiles(16).
//   - per block one 16x16 output tile; 4 waves K-split (128 each) so weight
//     fragments stay register-resident (R4: VGPR=56, no remat).
//   - publish: per-wave vmcnt(0) drain -> __syncthreads -> ONE plain relaxed
//     agent store slots[g][blk]=t+1 (no RMW, no contention).
//   - poll: wave-wide load of the group's 32 slots (one cacheline) +
//     __all(slot >= target).
//   - rotating (T+1)-slab h buffers; kernel-dispatch acquire invalidates L2s,
//     in-kernel addresses are first-touch -> normal loads safe after gate.
// ---------------------------------------------------------------------------

#define kB 64
#define kT 512
#define kI 256
#define kH 512
#define kBH (kB * kH)   // 32768

typedef _Float16 half8 __attribute__((ext_vector_type(8)));
typedef _Float16 half4v __attribute__((ext_vector_type(4)));
typedef float floatx4 __attribute__((ext_vector_type(4)));

// ws layout (bytes)
constexpr size_t X16_B   = 0;                                    // [B][T][I] fp16
constexpr size_t OUT0M_B = 16u * 1024 * 1024;                    // [T+1][B][H] fp16
constexpr size_t H1M_B   = OUT0M_B + (size_t)(kT + 1) * kBH * 2; // [T+1][B][H] fp16
constexpr size_t CNT_B   = H1M_B + (size_t)(kT + 1) * kBH * 2;   // slots0[4][32], slots1[4][32]

__device__ inline half8 cvt8(const float* p) {
    const float4* p4 = (const float4*)p;
    float4 a = p4[0], b = p4[1];
    half8 h;
    h[0] = (_Float16)a.x; h[1] = (_Float16)a.y; h[2] = (_Float16)a.z; h[3] = (_Float16)a.w;
    h[4] = (_Float16)b.x; h[5] = (_Float16)b.y; h[6] = (_Float16)b.z; h[7] = (_Float16)b.w;
    return h;
}

__device__ inline void sc_store_half(_Float16* p, _Float16 v) {
    unsigned short u = __builtin_bit_cast(unsigned short, v);
    __hip_atomic_store((unsigned short*)p, u, __ATOMIC_RELAXED, __HIP_MEMORY_SCOPE_AGENT);
}

// all lanes watch slot (lane&31); exit when every slot >= target
__device__ inline void wait_slots(const int* slots, int target) {
    const int* p = slots + (threadIdx.x & 31);
    int guard = 0;
    for (;;) {
        int v = __hip_atomic_load(p, __ATOMIC_RELAXED, __HIP_MEMORY_SCOPE_AGENT);
        if (__all(v >= target)) break;
        if (++guard > 50000000) break;  // fail-wrong, not hang
    }
    asm volatile("" ::: "memory");  // keep slab loads below the gate
}

// whole block: drain stores to LLC, then one plain flag store (no RMW)
__device__ inline void publish_block(int* slot, int t1, int tid) {
    asm volatile("" ::: "memory");
    __builtin_amdgcn_s_waitcnt(0x0F70);  // vmcnt(0) for this wave
    __syncthreads();                     // all waves drained
    if (tid == 0)
        __hip_atomic_store(slot, t1, __ATOMIC_RELAXED, __HIP_MEMORY_SCOPE_AGENT);
}

__global__ void cvt_x_kernel(const float* __restrict__ x, _Float16* __restrict__ x16) {
    size_t i = ((size_t)blockIdx.x * blockDim.x + threadIdx.x) * 4;
    size_t stride = (size_t)gridDim.x * blockDim.x * 4;
    const size_t n = (size_t)kB * kT * kI;
    for (; i < n; i += stride) {
        float4 v = *(const float4*)(x + i);
        half4v h;
        h[0] = (_Float16)v.x; h[1] = (_Float16)v.y; h[2] = (_Float16)v.z; h[3] = (_Float16)v.w;
        *(half4v*)(x16 + i) = h;
    }
}

__global__ void setup_kernel(const float* __restrict__ h0, _Float16* __restrict__ out0m,
                             _Float16* __restrict__ h1m, int* __restrict__ cnt) {
    int idx = blockIdx.x * blockDim.x + threadIdx.x;  // 0 .. 65535
    if (idx < kBH) out0m[idx] = (_Float16)h0[idx];
    else h1m[idx - kBH] = (_Float16)h0[idx];
    if (idx < 256) cnt[idx] = 0;
}

__global__ __launch_bounds__(256, 1) void scan_kernel(
    const _Float16* __restrict__ x16, _Float16* __restrict__ out0m,
    _Float16* __restrict__ h1m, int* __restrict__ slots0, int* __restrict__ slots1,
    float* __restrict__ out1,
    const float* __restrict__ wih0, const float* __restrict__ whh0,
    const float* __restrict__ bih0, const float* __restrict__ bhh0,
    const float* __restrict__ wih1, const float* __restrict__ whh1,
    const float* __restrict__ bih1, const float* __restrict__ bhh1) {
    __shared__ float lds[2][4][256];   // [parity][wave][tile elems], 8 KB

    const int blk = blockIdx.x;
    const int tid = threadIdx.x;
    const int wave = tid >> 6;
    const int lane = tid & 63;
    const int r = lane & 15;   // MFMA row selector (A: batch, B: col)
    const int q = lane >> 4;   // MFMA k-subchunk
    const int layer = blk >> 7;
    const int lb = blk & 127;
    const int g = lb >> 5;             // batch group 0..3
    const int ct = lb & 31;            // col tile 0..31
    const int c0 = ct * 16;
    const int b0 = g * 16;

    // reduction-role mapping: this thread finalizes elem (row, col) of the tile
    const int col = lane & 15;
    const int row = wave * 4 + (lane >> 4);
    const int cc = c0 + col;           // output column
    const int bb = b0 + row;           // output batch
    const int roff = (wave * 16 + col) * 4 + (lane >> 4);

    if (layer == 0) {
        // ---------------- layer 0 ----------------
        half8 wfi[2], wfh[4];
#pragma unroll
        for (int m = 0; m < 2; ++m)
            wfi[m] = cvt8(wih0 + (size_t)(c0 + r) * kI + wave * 64 + m * 32 + q * 8);
#pragma unroll
        for (int m = 0; m < 4; ++m)
            wfh[m] = cvt8(whh0 + (size_t)(c0 + r) * kH + wave * 128 + m * 32 + q * 8);
        const float bias = bih0[cc] + bhh0[cc];
        int* gslots = slots0 + g * 32;

        for (int t = 0; t < kT; ++t) {
            // x projection for this wave's K-slice (pre-gate, latency-hidden)
            const _Float16* xrow = x16 + ((size_t)(b0 + r) * kT + t) * kI + wave * 64 + q * 8;
            half8 xa0 = *(const half8*)(xrow);
            half8 xa1 = *(const half8*)(xrow + 32);
            floatx4 a0 = {0.f, 0.f, 0.f, 0.f};
            floatx4 a1 = {0.f, 0.f, 0.f, 0.f};
            a0 = __builtin_amdgcn_mfma_f32_16x16x32_f16(xa0, wfi[0], a0, 0, 0, 0);
            a1 = __builtin_amdgcn_mfma_f32_16x16x32_f16(xa1, wfi[1], a1, 0, 0, 0);

            if (t > 0) wait_slots(gslots, t);   // slab t published by step t-1
            const _Float16* hrow = out0m + (size_t)t * kBH + (size_t)(b0 + r) * kH
                                   + wave * 128 + q * 8;
            half8 h0v = *(const half8*)(hrow);
            half8 h1v = *(const half8*)(hrow + 32);
            half8 h2v = *(const half8*)(hrow + 64);
            half8 h3v = *(const half8*)(hrow + 96);
            a0 = __builtin_amdgcn_mfma_f32_16x16x32_f16(h0v, wfh[0], a0, 0, 0, 0);
            a1 = __builtin_amdgcn_mfma_f32_16x16x32_f16(h1v, wfh[1], a1, 0, 0, 0);
            a0 = __builtin_amdgcn_mfma_f32_16x16x32_f16(h2v, wfh[2], a0, 0, 0, 0);
            a1 = __builtin_amdgcn_mfma_f32_16x16x32_f16(h3v, wfh[3], a1, 0, 0, 0);

            *(floatx4*)(&lds[t & 1][wave][lane * 4]) = a0 + a1;
            __syncthreads();
            const float* lp = &lds[t & 1][0][0];
            float s = lp[roff] + lp[256 + roff] + lp[512 + roff] + lp[768 + roff];
            float v = tanhf(s + bias);
            sc_store_half(out0m + (size_t)(t + 1) * kBH + (size_t)bb * kH + cc, (_Float16)v);
            publish_block(&gslots[ct], t + 1, tid);
        }
    } else {
        // ---------------- layer 1 ----------------
        half8 wfi[4], wfh[4];
#pragma unroll
        for (int m = 0; m < 4; ++m)
            wfi[m] = cvt8(wih1 + (size_t)(c0 + r) * kH + wave * 128 + m * 32 + q * 8);
#pragma unroll
        for (int m = 0; m < 4; ++m)
            wfh[m] = cvt8(whh1 + (size_t)(c0 + r) * kH + wave * 128 + m * 32 + q * 8);
        const float bias = bih1[cc] + bhh1[cc];
        int* g0slots = slots0 + g * 32;
        int* g1slots = slots1 + g * 32;

        for (int t = 0; t < kT; ++t) {
            floatx4 a0 = {0.f, 0.f, 0.f, 0.f};
            floatx4 a1 = {0.f, 0.f, 0.f, 0.f};
            // gate A: own h from t-1 (slab t) -- usually already satisfied
            if (t > 0) wait_slots(g1slots, t);
            const _Float16* hrow = h1m + (size_t)t * kBH + (size_t)(b0 + r) * kH
                                   + wave * 128 + q * 8;
            half8 h0v = *(const half8*)(hrow);
            half8 h1v = *(const half8*)(hrow + 32);
            half8 h2v = *(const half8*)(hrow + 64);
            half8 h3v = *(const half8*)(hrow + 96);
            a0 = __builtin_amdgcn_mfma_f32_16x16x32_f16(h0v, wfh[0], a0, 0, 0, 0);
            a1 = __builtin_amdgcn_mfma_f32_16x16x32_f16(h1v, wfh[1], a1, 0, 0, 0);
            a0 = __builtin_amdgcn_mfma_f32_16x16x32_f16(h2v, wfh[2], a0, 0, 0, 0);
            a1 = __builtin_amdgcn_mfma_f32_16x16x32_f16(h3v, wfh[3], a1, 0, 0, 0);
            // gate B: layer0 output for t (slab t+1) -- the fresh dependency
            wait_slots(g0slots, t + 1);
            const _Float16* irow = out0m + (size_t)(t + 1) * kBH + (size_t)(b0 + r) * kH
                                   + wave * 128 + q * 8;
            half8 i0 = *(const half8*)(irow);
            half8 i1 = *(const half8*)(irow + 32);
            half8 i2 = *(const half8*)(irow + 64);
            half8 i3 = *(const half8*)(irow + 96);
            a0 = __builtin_amdgcn_mfma_f32_16x16x32_f16(i0, wfi[0], a0, 0, 0, 0);
            a1 = __builtin_amdgcn_mfma_f32_16x16x32_f16(i1, wfi[1], a1, 0, 0, 0);
            a0 = __builtin_amdgcn_mfma_f32_16x16x32_f16(i2, wfi[2], a0, 0, 0, 0);
            a1 = __builtin_amdgcn_mfma_f32_16x16x32_f16(i3, wfi[3], a1, 0, 0, 0);

            *(floatx4*)(&lds[t & 1][wave][lane * 4]) = a0 + a1;
            __syncthreads();
            const float* lp = &lds[t & 1][0][0];
            float s = lp[roff] + lp[256 + roff] + lp[512 + roff] + lp[768 + roff];
            float v = tanhf(s + bias);
            out1[((size_t)bb * kT + t) * kH + cc] = v;   // fp32 output
            sc_store_half(h1m + (size_t)(t + 1) * kBH + (size_t)bb * kH + cc, (_Float16)v);
            publish_block(&g1slots[ct], t + 1, tid);
        }
    }
}

__global__ void finalize_kernel(const _Float16* __restrict__ out0m,
                                const _Float16* __restrict__ h1m,
                                float* __restrict__ out) {
    int idx = blockIdx.x * blockDim.x + threadIdx.x;  // 0 .. 65535
    float* hn = out + (size_t)kB * kT * kH;
    if (idx < kBH) hn[idx] = (float)out0m[(size_t)kT * kBH + idx];
    else hn[idx] = (float)h1m[(size_t)kT * kBH + (idx - kBH)];
}

extern "C" void kernel_launch(void* const* d_in, const int* in_sizes, int n_in,
                              void* d_out, int out_size, void* d_ws, size_t ws_size,
                              hipStream_t stream) {
    const float* x    = (const float*)d_in[0];
    const float* h0in = (const float*)d_in[1];
    const float* wih0 = (const float*)d_in[2];
    const float* whh0 = (const float*)d_in[3];
    const float* bih0 = (const float*)d_in[4];
    const float* bhh0 = (const float*)d_in[5];
    const float* wih1 = (const float*)d_in[6];
    const float* whh1 = (const float*)d_in[7];
    const float* bih1 = (const float*)d_in[8];
    const float* bhh1 = (const float*)d_in[9];
    float* out = (float*)d_out;
    char* ws = (char*)d_ws;

    _Float16* x16   = (_Float16*)(ws + X16_B);
    _Float16* out0m = (_Float16*)(ws + OUT0M_B);
    _Float16* h1m   = (_Float16*)(ws + H1M_B);
    int* cnt        = (int*)(ws + CNT_B);
    int* slots0 = cnt;          // [4][32]
    int* slots1 = cnt + 128;    // [4][32]

    cvt_x_kernel<<<1024, 256, 0, stream>>>(x, x16);
    setup_kernel<<<(2 * kBH) / 256, 256, 0, stream>>>(h0in, out0m, h1m, cnt);
    scan_kernel<<<256, 256, 0, stream>>>(x16, out0m, h1m, slots0, slots1, out,
                                         wih0, whh0, bih0, bhh0, wih1, whh1, bih1, bhh1);
    finalize_kernel<<<(2 * kBH) / 256, 256, 0, stream>>>(out0m, h1m, out);
}